// Round 1
// baseline (348.152 us; speedup 1.0000x reference)
//
#include <hip/hip_runtime.h>

// NEAT batched forward: B=4096 genomes, N=256 nodes, E=4096 conns, 3 update layers.
// One block per genome; thread t owns node t and 16 connections (in registers).
// vals/agg/in_cnt live in LDS; scatter-add via shared-memory atomics.

#define NN        256
#define NE        4096
#define NIN       64
#define NOUT      8
#define NTHREADS  256
#define CPT       (NE / NTHREADS)   // 16 connections per thread

__global__ __launch_bounds__(NTHREADS) void neat_fwd(
    const float* __restrict__ inputs,      // [B,64]
    const int*   __restrict__ node_layer,  // [B,256]
    const int*   __restrict__ conn_in,     // [B,4096]
    const int*   __restrict__ conn_out,    // [B,4096]
    const float* __restrict__ conn_w,      // [B,4096]
    const unsigned char* __restrict__ conn_en, // [B,4096] bool (layout detected)
    float*       __restrict__ out)         // [B,8]
{
    const int b = blockIdx.x;
    const int t = threadIdx.x;

    __shared__ float vals[NN];
    __shared__ float agg[NN];
    __shared__ float in_cnt[NN];

    // --- detect conn_enabled element width: 1-byte bools vs int32 ---
    // Byte-packed random 0/1 bools make >1 words almost surely; int32 bools are all 0/1.
    const unsigned int* en_w = (const unsigned int*)conn_en;
    bool byte_mode = false;
#pragma unroll
    for (int i = 0; i < 16; ++i) byte_mode |= (en_w[i] > 1u);

    // --- init node values & in-counts ---
    vals[t]   = (t < NIN) ? inputs[(size_t)b * NIN + t] : 0.0f;
    in_cnt[t] = 0.0f;
    const int nl = node_layer[(size_t)b * NN + t];
    __syncthreads();

    // --- load this thread's 16 connections (coalesced 16B vec loads), scatter in_cnt ---
    int      ci[CPT];
    int      co[CPT];
    float    w[CPT];
    unsigned en_mask = 0;

    const int4*   ci4 = (const int4*)(conn_in  + (size_t)b * NE);
    const int4*   co4 = (const int4*)(conn_out + (size_t)b * NE);
    const float4* w4  = (const float4*)(conn_w  + (size_t)b * NE);

#pragma unroll
    for (int k = 0; k < CPT / 4; ++k) {
        const int idx = t + k * NTHREADS;   // vec4 index, coalesced across lanes
        int4   a  = ci4[idx];
        int4   c  = co4[idx];
        float4 ww = w4[idx];
        int e0, e1, e2, e3;
        if (byte_mode) {
            const uchar4* en4 = (const uchar4*)(conn_en + (size_t)b * NE);
            uchar4 e = en4[idx];
            e0 = e.x; e1 = e.y; e2 = e.z; e3 = e.w;
        } else {
            const int4* en4 = (const int4*)((const int*)conn_en + (size_t)b * NE);
            int4 e = en4[idx];
            e0 = e.x; e1 = e.y; e2 = e.z; e3 = e.w;
        }
        ci[4*k+0] = a.x; ci[4*k+1] = a.y; ci[4*k+2] = a.z; ci[4*k+3] = a.w;
        co[4*k+0] = c.x; co[4*k+1] = c.y; co[4*k+2] = c.z; co[4*k+3] = c.w;
        w [4*k+0] = ww.x; w [4*k+1] = ww.y; w [4*k+2] = ww.z; w [4*k+3] = ww.w;
        if (e0) { en_mask |= 1u << (4*k+0); atomicAdd(&in_cnt[c.x], 1.0f); }
        if (e1) { en_mask |= 1u << (4*k+1); atomicAdd(&in_cnt[c.y], 1.0f); }
        if (e2) { en_mask |= 1u << (4*k+2); atomicAdd(&in_cnt[c.z], 1.0f); }
        if (e3) { en_mask |= 1u << (4*k+3); atomicAdd(&in_cnt[c.w], 1.0f); }
    }
    __syncthreads();

    const bool node_active = (in_cnt[t] > 0.0f);

    // --- 3 layer-synchronous passes ---
#pragma unroll
    for (int layer = 1; layer < 4; ++layer) {
        agg[t] = 0.0f;
        __syncthreads();
#pragma unroll
        for (int j = 0; j < CPT; ++j) {
            if (en_mask & (1u << j))
                atomicAdd(&agg[co[j]], vals[ci[j]] * w[j]);
        }
        __syncthreads();
        if (nl == layer && node_active)
            vals[t] = tanhf(agg[t]);
        __syncthreads();
    }

    if (t < NOUT)
        out[(size_t)b * NOUT + t] = vals[NIN + t];
}

extern "C" void kernel_launch(void* const* d_in, const int* in_sizes, int n_in,
                              void* d_out, int out_size, void* d_ws, size_t ws_size,
                              hipStream_t stream) {
    const float* inputs        = (const float*)d_in[0];
    const int*   node_layer    = (const int*)d_in[1];
    const int*   conn_in       = (const int*)d_in[2];
    const int*   conn_out      = (const int*)d_in[3];
    const float* conn_w        = (const float*)d_in[4];
    const unsigned char* conn_en = (const unsigned char*)d_in[5];
    float* out = (float*)d_out;

    const int B = in_sizes[0] / NIN;   // 4096
    neat_fwd<<<B, NTHREADS, 0, stream>>>(inputs, node_layer, conn_in, conn_out,
                                         conn_w, conn_en, out);
}

// Round 2
// 339.623 us; speedup vs baseline: 1.0251x; 1.0251x over previous
//
#include <hip/hip_runtime.h>

// NEAT batched forward: B=4096 genomes, N=256 nodes, E=4096 conns, 3 update layers.
// One block per genome; thread t owns node t and 16 connections held in NAMED
// int4/float4 registers (R1 lesson: indexed arrays got demoted, VGPR_Count=32).
// vals/agg/in_cnt live in LDS; scatter-add via masked shared-memory atomics.

#define NN        256
#define NE        4096
#define NIN       64
#define NOUT      8
#define NTHREADS  256

__global__ __launch_bounds__(NTHREADS) void neat_fwd(
    const float* __restrict__ inputs,      // [B,64]
    const int*   __restrict__ node_layer,  // [B,256]
    const int*   __restrict__ conn_in,     // [B,4096]
    const int*   __restrict__ conn_out,    // [B,4096]
    const float* __restrict__ conn_w,      // [B,4096]
    const unsigned char* __restrict__ conn_en, // [B,4096] bool (layout detected)
    float*       __restrict__ out)         // [B,8]
{
    const int b = blockIdx.x;
    const int t = threadIdx.x;

    __shared__ float vals[NN];
    __shared__ float agg[NN];
    __shared__ float in_cnt[NN];

    // --- detect conn_enabled element width: 1-byte bools vs int32 (uniform) ---
    const unsigned int* en_w = (const unsigned int*)conn_en;
    bool byte_mode = false;
#pragma unroll
    for (int i = 0; i < 16; ++i) byte_mode |= (en_w[i] > 1u);

    // --- init node values & in-counts ---
    vals[t]   = (t < NIN) ? inputs[(size_t)b * NIN + t] : 0.0f;
    in_cnt[t] = 0.0f;
    const int nl = node_layer[(size_t)b * NN + t];
    __syncthreads();

    // --- load 16 connections into NAMED registers (coalesced 16B vec loads) ---
    const int4*   ci4 = (const int4*)(conn_in  + (size_t)b * NE);
    const int4*   co4 = (const int4*)(conn_out + (size_t)b * NE);
    const float4* w4  = (const float4*)(conn_w  + (size_t)b * NE);

    int4 a0 = ci4[t            ];
    int4 a1 = ci4[t + 1*NTHREADS];
    int4 a2 = ci4[t + 2*NTHREADS];
    int4 a3 = ci4[t + 3*NTHREADS];
    int4 c0 = co4[t            ];
    int4 c1 = co4[t + 1*NTHREADS];
    int4 c2 = co4[t + 2*NTHREADS];
    int4 c3 = co4[t + 3*NTHREADS];
    float4 w0 = w4[t            ];
    float4 w1 = w4[t + 1*NTHREADS];
    float4 w2 = w4[t + 2*NTHREADS];
    float4 w3 = w4[t + 3*NTHREADS];

    unsigned m = 0;
    if (byte_mode) {
        const uchar4* e4 = (const uchar4*)(conn_en + (size_t)b * NE);
        uchar4 e0 = e4[t            ];
        uchar4 e1 = e4[t + 1*NTHREADS];
        uchar4 e2 = e4[t + 2*NTHREADS];
        uchar4 e3 = e4[t + 3*NTHREADS];
        m = (e0.x ? 1u<<0  : 0u) | (e0.y ? 1u<<1  : 0u) | (e0.z ? 1u<<2  : 0u) | (e0.w ? 1u<<3  : 0u)
          | (e1.x ? 1u<<4  : 0u) | (e1.y ? 1u<<5  : 0u) | (e1.z ? 1u<<6  : 0u) | (e1.w ? 1u<<7  : 0u)
          | (e2.x ? 1u<<8  : 0u) | (e2.y ? 1u<<9  : 0u) | (e2.z ? 1u<<10 : 0u) | (e2.w ? 1u<<11 : 0u)
          | (e3.x ? 1u<<12 : 0u) | (e3.y ? 1u<<13 : 0u) | (e3.z ? 1u<<14 : 0u) | (e3.w ? 1u<<15 : 0u);
    } else {
        const int4* e4 = (const int4*)((const int*)conn_en + (size_t)b * NE);
        int4 e0 = e4[t            ];
        int4 e1 = e4[t + 1*NTHREADS];
        int4 e2 = e4[t + 2*NTHREADS];
        int4 e3 = e4[t + 3*NTHREADS];
        m = (e0.x ? 1u<<0  : 0u) | (e0.y ? 1u<<1  : 0u) | (e0.z ? 1u<<2  : 0u) | (e0.w ? 1u<<3  : 0u)
          | (e1.x ? 1u<<4  : 0u) | (e1.y ? 1u<<5  : 0u) | (e1.z ? 1u<<6  : 0u) | (e1.w ? 1u<<7  : 0u)
          | (e2.x ? 1u<<8  : 0u) | (e2.y ? 1u<<9  : 0u) | (e2.z ? 1u<<10 : 0u) | (e2.w ? 1u<<11 : 0u)
          | (e3.x ? 1u<<12 : 0u) | (e3.y ? 1u<<13 : 0u) | (e3.z ? 1u<<14 : 0u) | (e3.w ? 1u<<15 : 0u);
    }

    // --- in-count scatter (masked LDS atomics) ---
    if (m & (1u<<0))  atomicAdd(&in_cnt[c0.x], 1.0f);
    if (m & (1u<<1))  atomicAdd(&in_cnt[c0.y], 1.0f);
    if (m & (1u<<2))  atomicAdd(&in_cnt[c0.z], 1.0f);
    if (m & (1u<<3))  atomicAdd(&in_cnt[c0.w], 1.0f);
    if (m & (1u<<4))  atomicAdd(&in_cnt[c1.x], 1.0f);
    if (m & (1u<<5))  atomicAdd(&in_cnt[c1.y], 1.0f);
    if (m & (1u<<6))  atomicAdd(&in_cnt[c1.z], 1.0f);
    if (m & (1u<<7))  atomicAdd(&in_cnt[c1.w], 1.0f);
    if (m & (1u<<8))  atomicAdd(&in_cnt[c2.x], 1.0f);
    if (m & (1u<<9))  atomicAdd(&in_cnt[c2.y], 1.0f);
    if (m & (1u<<10)) atomicAdd(&in_cnt[c2.z], 1.0f);
    if (m & (1u<<11)) atomicAdd(&in_cnt[c2.w], 1.0f);
    if (m & (1u<<12)) atomicAdd(&in_cnt[c3.x], 1.0f);
    if (m & (1u<<13)) atomicAdd(&in_cnt[c3.y], 1.0f);
    if (m & (1u<<14)) atomicAdd(&in_cnt[c3.z], 1.0f);
    if (m & (1u<<15)) atomicAdd(&in_cnt[c3.w], 1.0f);
    __syncthreads();

    const bool node_active = (in_cnt[t] > 0.0f);

#define CONN_EDGE(BIT, CI, CO, W) \
    if (m & (1u<<BIT)) atomicAdd(&agg[CO], vals[CI] * (W));

    // --- 3 layer-synchronous passes ---
#pragma unroll
    for (int layer = 1; layer < 4; ++layer) {
        agg[t] = 0.0f;
        __syncthreads();
        CONN_EDGE(0,  a0.x, c0.x, w0.x)
        CONN_EDGE(1,  a0.y, c0.y, w0.y)
        CONN_EDGE(2,  a0.z, c0.z, w0.z)
        CONN_EDGE(3,  a0.w, c0.w, w0.w)
        CONN_EDGE(4,  a1.x, c1.x, w1.x)
        CONN_EDGE(5,  a1.y, c1.y, w1.y)
        CONN_EDGE(6,  a1.z, c1.z, w1.z)
        CONN_EDGE(7,  a1.w, c1.w, w1.w)
        CONN_EDGE(8,  a2.x, c2.x, w2.x)
        CONN_EDGE(9,  a2.y, c2.y, w2.y)
        CONN_EDGE(10, a2.z, c2.z, w2.z)
        CONN_EDGE(11, a2.w, c2.w, w2.w)
        CONN_EDGE(12, a3.x, c3.x, w3.x)
        CONN_EDGE(13, a3.y, c3.y, w3.y)
        CONN_EDGE(14, a3.z, c3.z, w3.z)
        CONN_EDGE(15, a3.w, c3.w, w3.w)
        __syncthreads();
        if (nl == layer && node_active)
            vals[t] = tanhf(agg[t]);
        __syncthreads();
    }

    if (t < NOUT)
        out[(size_t)b * NOUT + t] = vals[NIN + t];
}

extern "C" void kernel_launch(void* const* d_in, const int* in_sizes, int n_in,
                              void* d_out, int out_size, void* d_ws, size_t ws_size,
                              hipStream_t stream) {
    const float* inputs          = (const float*)d_in[0];
    const int*   node_layer      = (const int*)d_in[1];
    const int*   conn_in         = (const int*)d_in[2];
    const int*   conn_out        = (const int*)d_in[3];
    const float* conn_w          = (const float*)d_in[4];
    const unsigned char* conn_en = (const unsigned char*)d_in[5];
    float* out = (float*)d_out;

    const int B = in_sizes[0] / NIN;   // 4096
    neat_fwd<<<B, NTHREADS, 0, stream>>>(inputs, node_layer, conn_in, conn_out,
                                         conn_w, conn_en, out);
}

// Round 3
// 254.386 us; speedup vs baseline: 1.3686x; 1.3351x over previous
//
#include <hip/hip_runtime.h>

// NEAT batched forward, bucket-sorted edition.
// Key insights vs R2 (which was DS-pipe bound on masked random-scatter atomics):
//  1) An edge only matters in the layer of its TARGET node -> bucket edges by
//     target-layer once, visit each live edge exactly once (was 3x all edges).
//  2) Edges that are disabled or target layer-0 nodes are dead -> dropped at
//     build time (~63% of edges).
//  3) in_count mask is a semantic no-op (tanh(0)==0 == kept init value) -> deleted.
// Bucketing uses wave ballots (idle VALU pipe), zero same-address atomic contention.

#define NN   256
#define NE   4096
#define NIN  64
#define NOUT 8
#define NT   256
#define NWAVE 4

__global__ __launch_bounds__(NT) void neat_fwd(
    const float* __restrict__ inputs,          // [B,64]
    const int*   __restrict__ node_layer,      // [B,256]
    const int*   __restrict__ conn_in,         // [B,4096]
    const int*   __restrict__ conn_out,        // [B,4096]
    const float* __restrict__ conn_w,          // [B,4096]
    const unsigned char* __restrict__ conn_en, // [B,4096] bool (layout sniffed)
    float*       __restrict__ out)             // [B,8]
{
    const int b    = blockIdx.x;
    const int t    = threadIdx.x;
    const int wave = t >> 6;
    const int lane = t & 63;
    const unsigned long long lmlt = (1ull << lane) - 1ull;

    __shared__ float vals[NN];
    __shared__ float agg[NN];
    __shared__ int   nl_sh[NN];
    __shared__ uint2 edges[NE];          // {w as u32, src | (tgt<<16)}
    __shared__ int   wave_cnt[NWAVE][3];
    __shared__ int   wave_base[NWAVE][3];
    __shared__ int   Loff[5];            // bucket k occupies [Loff[k], Loff[k+1])

    // --- sniff conn_enabled element width (uniform): byte bools vs int32 ---
    const unsigned int* en_w = (const unsigned int*)conn_en;
    bool byte_mode = false;
#pragma unroll
    for (int i = 0; i < 16; ++i) byte_mode |= (en_w[i] > 1u);

    // --- init LDS state ---
    const int nl = node_layer[(size_t)b * NN + t];
    nl_sh[t] = nl;
    vals[t]  = (t < NIN) ? inputs[(size_t)b * NIN + t] : 0.0f;

    // --- load 16 connections into NAMED registers (coalesced 16B vec loads) ---
    const int4*   ci4 = (const int4*)(conn_in  + (size_t)b * NE);
    const int4*   co4 = (const int4*)(conn_out + (size_t)b * NE);
    const float4* w4  = (const float4*)(conn_w  + (size_t)b * NE);

    int4 a0 = ci4[t             ];
    int4 a1 = ci4[t + 1*NT      ];
    int4 a2 = ci4[t + 2*NT      ];
    int4 a3 = ci4[t + 3*NT      ];
    int4 c0 = co4[t             ];
    int4 c1 = co4[t + 1*NT      ];
    int4 c2 = co4[t + 2*NT      ];
    int4 c3 = co4[t + 3*NT      ];
    float4 w0 = w4[t            ];
    float4 w1 = w4[t + 1*NT     ];
    float4 w2 = w4[t + 2*NT     ];
    float4 w3 = w4[t + 3*NT     ];

    unsigned m = 0;
    if (byte_mode) {
        const uchar4* e4 = (const uchar4*)(conn_en + (size_t)b * NE);
        uchar4 e0 = e4[t       ];
        uchar4 e1 = e4[t + 1*NT];
        uchar4 e2 = e4[t + 2*NT];
        uchar4 e3 = e4[t + 3*NT];
        m = (e0.x ? 1u<<0  : 0u) | (e0.y ? 1u<<1  : 0u) | (e0.z ? 1u<<2  : 0u) | (e0.w ? 1u<<3  : 0u)
          | (e1.x ? 1u<<4  : 0u) | (e1.y ? 1u<<5  : 0u) | (e1.z ? 1u<<6  : 0u) | (e1.w ? 1u<<7  : 0u)
          | (e2.x ? 1u<<8  : 0u) | (e2.y ? 1u<<9  : 0u) | (e2.z ? 1u<<10 : 0u) | (e2.w ? 1u<<11 : 0u)
          | (e3.x ? 1u<<12 : 0u) | (e3.y ? 1u<<13 : 0u) | (e3.z ? 1u<<14 : 0u) | (e3.w ? 1u<<15 : 0u);
    } else {
        const int4* e4 = (const int4*)((const int*)conn_en + (size_t)b * NE);
        int4 e0 = e4[t       ];
        int4 e1 = e4[t + 1*NT];
        int4 e2 = e4[t + 2*NT];
        int4 e3 = e4[t + 3*NT];
        m = (e0.x ? 1u<<0  : 0u) | (e0.y ? 1u<<1  : 0u) | (e0.z ? 1u<<2  : 0u) | (e0.w ? 1u<<3  : 0u)
          | (e1.x ? 1u<<4  : 0u) | (e1.y ? 1u<<5  : 0u) | (e1.z ? 1u<<6  : 0u) | (e1.w ? 1u<<7  : 0u)
          | (e2.x ? 1u<<8  : 0u) | (e2.y ? 1u<<9  : 0u) | (e2.z ? 1u<<10 : 0u) | (e2.w ? 1u<<11 : 0u)
          | (e3.x ? 1u<<12 : 0u) | (e3.y ? 1u<<13 : 0u) | (e3.z ? 1u<<14 : 0u) | (e3.w ? 1u<<15 : 0u);
    }
    __syncthreads();   // nl_sh ready

    // --- pass 1: per-edge key = enabled ? layer(target) : 0 ; count per wave ---
    unsigned keys = 0;
    int c1n = 0, c2n = 0, c3n = 0;
#define KEYSLOT(J, CO) { \
        int kk = nl_sh[(CO)]; \
        kk = ((m >> (J)) & 1u) ? kk : 0; \
        keys |= (unsigned)kk << (2*(J)); \
        c1n += (kk == 1); c2n += (kk == 2); c3n += (kk == 3); }
    KEYSLOT(0,  c0.x) KEYSLOT(1,  c0.y) KEYSLOT(2,  c0.z) KEYSLOT(3,  c0.w)
    KEYSLOT(4,  c1.x) KEYSLOT(5,  c1.y) KEYSLOT(6,  c1.z) KEYSLOT(7,  c1.w)
    KEYSLOT(8,  c2.x) KEYSLOT(9,  c2.y) KEYSLOT(10, c2.z) KEYSLOT(11, c2.w)
    KEYSLOT(12, c3.x) KEYSLOT(13, c3.y) KEYSLOT(14, c3.z) KEYSLOT(15, c3.w)
#undef KEYSLOT

#pragma unroll
    for (int off = 32; off > 0; off >>= 1) {
        c1n += __shfl_down(c1n, off);
        c2n += __shfl_down(c2n, off);
        c3n += __shfl_down(c3n, off);
    }
    if (lane == 0) {
        wave_cnt[wave][0] = c1n;
        wave_cnt[wave][1] = c2n;
        wave_cnt[wave][2] = c3n;
    }
    __syncthreads();

    // --- scan: layer offsets + per-wave bases (single thread, tiny) ---
    if (t == 0) {
        int T1 = 0, T2 = 0, T3 = 0;
#pragma unroll
        for (int w = 0; w < NWAVE; ++w) {
            T1 += wave_cnt[w][0]; T2 += wave_cnt[w][1]; T3 += wave_cnt[w][2];
        }
        Loff[1] = 0; Loff[2] = T1; Loff[3] = T1 + T2; Loff[4] = T1 + T2 + T3;
        int r1 = 0, r2 = 0, r3 = 0;
#pragma unroll
        for (int w = 0; w < NWAVE; ++w) {
            wave_base[w][0] = 0       + r1; r1 += wave_cnt[w][0];
            wave_base[w][1] = T1      + r2; r2 += wave_cnt[w][1];
            wave_base[w][2] = T1 + T2 + r3; r3 += wave_cnt[w][2];
        }
    }
    __syncthreads();

    // --- pass 2: ballot-ordered scatter into bucketed edge array ---
    int base1 = wave_base[wave][0];
    int base2 = wave_base[wave][1];
    int base3 = wave_base[wave][2];
#define SCAT(J, CI, CO, W) { \
        int kk = (int)((keys >> (2*(J))) & 3u); \
        unsigned long long B1 = __ballot(kk == 1); \
        unsigned long long B2 = __ballot(kk == 2); \
        unsigned long long B3 = __ballot(kk == 3); \
        if (kk) { \
            unsigned long long bk = (kk == 1) ? B1 : ((kk == 2) ? B2 : B3); \
            int bs = (kk == 1) ? base1 : ((kk == 2) ? base2 : base3); \
            int pos = bs + __popcll(bk & lmlt); \
            edges[pos] = make_uint2(__float_as_uint(W), \
                                    (unsigned)(CI) | ((unsigned)(CO) << 16)); \
        } \
        base1 += __popcll(B1); base2 += __popcll(B2); base3 += __popcll(B3); }
    SCAT(0,  a0.x, c0.x, w0.x) SCAT(1,  a0.y, c0.y, w0.y)
    SCAT(2,  a0.z, c0.z, w0.z) SCAT(3,  a0.w, c0.w, w0.w)
    SCAT(4,  a1.x, c1.x, w1.x) SCAT(5,  a1.y, c1.y, w1.y)
    SCAT(6,  a1.z, c1.z, w1.z) SCAT(7,  a1.w, c1.w, w1.w)
    SCAT(8,  a2.x, c2.x, w2.x) SCAT(9,  a2.y, c2.y, w2.y)
    SCAT(10, a2.z, c2.z, w2.z) SCAT(11, a2.w, c2.w, w2.w)
    SCAT(12, a3.x, c3.x, w3.x) SCAT(13, a3.y, c3.y, w3.y)
    SCAT(14, a3.z, c3.z, w3.z) SCAT(15, a3.w, c3.w, w3.w)
#undef SCAT
    __syncthreads();   // edges + vals ready

    // --- 3 layer-synchronous passes over ONLY that layer's edges ---
#pragma unroll
    for (int L = 1; L < 4; ++L) {
        agg[t] = 0.0f;
        __syncthreads();
        const int s = Loff[L], e = Loff[L + 1];
        for (int p = s + t; p < e; p += NT) {
            uint2 ed = edges[p];
            const int src = (int)(ed.y & 0xFFFFu);
            const int tgt = (int)(ed.y >> 16);
            atomicAdd(&agg[tgt], vals[src] * __uint_as_float(ed.x));
        }
        __syncthreads();
        if (nl == L)
            vals[t] = tanhf(agg[t]);   // in_count mask provably redundant
        __syncthreads();
    }

    if (t < NOUT)
        out[(size_t)b * NOUT + t] = vals[NIN + t];
}

extern "C" void kernel_launch(void* const* d_in, const int* in_sizes, int n_in,
                              void* d_out, int out_size, void* d_ws, size_t ws_size,
                              hipStream_t stream) {
    const float* inputs          = (const float*)d_in[0];
    const int*   node_layer      = (const int*)d_in[1];
    const int*   conn_in         = (const int*)d_in[2];
    const int*   conn_out        = (const int*)d_in[3];
    const float* conn_w          = (const float*)d_in[4];
    const unsigned char* conn_en = (const unsigned char*)d_in[5];
    float* out = (float*)d_out;

    const int B = in_sizes[0] / NIN;   // 4096
    neat_fwd<<<B, NT, 0, stream>>>(inputs, node_layer, conn_in, conn_out,
                                   conn_w, conn_en, out);
}